// Round 2
// baseline (83.172 us; speedup 1.0000x reference)
//
#include <hip/hip_runtime.h>
#include <math.h>

#define NF 16
#define INV_2PI 0.15915494309189535f

// Single fused kernel: per-block coefficient prep (one wave -> LDS), then
// phase-folded Fourier sum: out = off' + sum_k R'_k * sin(2pi*(t*f'_k + phi'_k))
// using raw v_sin_f32 (revolutions semantics).
__global__ __launch_bounds__(256) void fourier_fused_kernel(
        const float* __restrict__ t,
        const float* __restrict__ freqs,
        const float* __restrict__ offp,
        const float* __restrict__ sc,
        const float* __restrict__ cc,
        float* __restrict__ out,
        int n4) {
    __shared__ float sh[3 * NF + 1];
    const int tid = threadIdx.x;

    if (tid < 64) {  // one wave does the prep
        float s = 0.f, c = 0.f, fq = 0.f;
        if (tid < NF) { s = sc[tid]; c = cc[tid]; fq = freqs[tid]; }
        float absum = fabsf(s) + fabsf(c);
        // butterfly over the 16 active lanes (lanes 16..63 hold 0)
        #pragma unroll
        for (int off = 1; off < NF; off <<= 1)
            absum += __shfl_xor(absum, off, 64);
        if (tid < NF) {
            float frange = fmaxf(1.0f, absum + 1e-8f);
            float inv = 1.0f / frange;
            float R   = sqrtf(s * s + c * c);
            float phi = atan2f(c, s);
            sh[tid]          = fq * INV_2PI;          // f' = f/(2pi)
            sh[NF + tid]     = phi * INV_2PI;         // phi' = phi/(2pi)
            sh[2 * NF + tid] = R * inv;               // R' = R/frange
            if (tid == 0) sh[3 * NF] = offp[0] * inv; // off' = offset/frange
        }
    }
    __syncthreads();

    float f2[NF], p2[NF], Rs[NF];
    #pragma unroll
    for (int k = 0; k < NF; ++k) {
        f2[k] = sh[k];
        p2[k] = sh[NF + k];
        Rs[k] = sh[2 * NF + k];
    }
    const float off = sh[3 * NF];

    const float4* __restrict__ t4 = (const float4*)t;
    float4* __restrict__ o4       = (float4*)out;

    int idx    = blockIdx.x * blockDim.x + tid;
    int stride = gridDim.x * blockDim.x;

    for (int i = idx; i < n4; i += stride) {
        float4 tv = t4[i];
        float tt[4] = {tv.x, tv.y, tv.z, tv.w};
        float acc[4];
        #pragma unroll
        for (int j = 0; j < 4; ++j) acc[j] = off;
        #pragma unroll
        for (int k = 0; k < NF; ++k) {
            #pragma unroll
            for (int j = 0; j < 4; ++j) {
                float r = fmaf(tt[j], f2[k], p2[k]);   // revolutions, |r| <~ 1.5
                acc[j] = fmaf(Rs[k], __builtin_amdgcn_sinf(r), acc[j]);
            }
        }
        float4 ov;
        ov.x = acc[0]; ov.y = acc[1]; ov.z = acc[2]; ov.w = acc[3];
        o4[i] = ov;
    }
}

extern "C" void kernel_launch(void* const* d_in, const int* in_sizes, int n_in,
                              void* d_out, int out_size, void* d_ws, size_t ws_size,
                              hipStream_t stream) {
    const float* t     = (const float*)d_in[0];
    const float* freqs = (const float*)d_in[1];
    const float* offp  = (const float*)d_in[2];
    const float* sc    = (const float*)d_in[3];
    const float* cc    = (const float*)d_in[4];
    float* out = (float*)d_out;
    (void)d_ws; (void)ws_size;

    int n4 = out_size / 4;              // 1048576 float4 groups
    int block = 256;
    int grid  = (n4 + block - 1) / block;  // 4096 blocks -> exactly 1 float4/thread
    if (grid > 4096) grid = 4096;          // safety: grid-stride covers the rest
    fourier_fused_kernel<<<grid, block, 0, stream>>>(t, freqs, offp, sc, cc, out, n4);
}